// Round 7
// baseline (75.150 us; speedup 1.0000x reference)
//
#include <hip/hip_runtime.h>
#include <hip/hip_fp16.h>
#include <math.h>

// Problem constants (match reference)
#define PH 256
#define PW 512
#define NRAYS (PH * PW)     // 131072
#define NS 300
#define NB64 (NRAYS / 64)   // 2048 one-wave blocks
#define PI_F 3.14159265358979323846f

// Padded volume: P[zp][yp][xp], zp in [0,66], yp/xp in [0,257].
// Logical (zz,y,x) = (zp-1, yp-1, xp-1); zz=0 -> ground 1000, zz in [1,64] ->
// voxel[zz-1], everything else (pads) = 0. Zero padding == reference's
// out-of-range gather = 0, so the render loop needs NO bounds logic at all.
#define XS 258
#define SS (258 * 258)          // 66564
#define ZSL 67
#define PVOX_ELEMS (ZSL * SS)   // 4,459,788
#define WS_VOL_OFF 32768

__device__ __forceinline__ float lerpf(float a, float b, float f) {
    return fmaf(f, b - a, a);
}

template <bool HALF>
__global__ __launch_bounds__(256)
void pack_kernel(const float* __restrict__ vox, void* __restrict__ pv,
                 int* __restrict__ mmi) {
    const int idx = blockIdx.x * 256 + threadIdx.x;
    if (idx == 0) {
        mmi[0] = 0x7f7fffff;   // FLT_MAX bits (min accumulator)
        mmi[1] = 0;            // 0.0f bits (max accumulator, depth >= 0)
    }
    if (idx >= PVOX_ELEMS) return;
    const int zp = idx / SS;
    const int rem = idx - zp * SS;
    const int yp = rem / XS;
    const int xp = rem - yp * XS;
    const int x = xp - 1, y = yp - 1, zz = zp - 1;
    float v = 0.0f;
    if (((unsigned)x < 256u) & ((unsigned)y < 256u)) {
        if (zz == 0) v = 1000.0f;
        else if ((unsigned)(zz - 1) < 64u) v = vox[((zz - 1) << 16) + (y << 8) + x];
    }
    if (HALF) ((__half*)pv)[idx] = __float2half_rn(v);
    else      ((float*)pv)[idx] = v;
}

template <bool HALF>
__device__ __forceinline__ float sample_sigma(const void* __restrict__ pvv,
                                              float fs, float sxd, float syd, float szd) {
    const float xf = fmaf(fs, sxd, 127.5f);
    const float yf = fmaf(fs, syd, 127.5f);
    const float zf = fmaf(fs, szd, 1.53125f);
    const float xw = floorf(xf), yw = floorf(yf), zw = floorf(zf);
    const float fx = xf - xw, fy = yf - yw, fz = zf - zw;
    const int x0 = (int)xw, y0 = (int)yw, z0 = (int)zw;
    const int off = z0 * SS + y0 * XS + x0 + (SS + XS + 1);   // +1 pad shift each axis
    float c000, c001, c010, c011, c100, c101, c110, c111;
    if (HALF) {
        const __half* p = (const __half*)pvv + off;
        c000 = __half2float(p[0]);       c001 = __half2float(p[1]);
        c010 = __half2float(p[XS]);      c011 = __half2float(p[XS + 1]);
        c100 = __half2float(p[SS]);      c101 = __half2float(p[SS + 1]);
        c110 = __half2float(p[SS + XS]); c111 = __half2float(p[SS + XS + 1]);
    } else {
        const float* p = (const float*)pvv + off;
        c000 = p[0];       c001 = p[1];
        c010 = p[XS];      c011 = p[XS + 1];
        c100 = p[SS];      c101 = p[SS + 1];
        c110 = p[SS + XS]; c111 = p[SS + XS + 1];
    }
    const float l00 = lerpf(c000, c001, fx);
    const float l01 = lerpf(c010, c011, fx);
    const float l10 = lerpf(c100, c101, fx);
    const float l11 = lerpf(c110, c111, fx);
    return lerpf(lerpf(l00, l01, fy), lerpf(l10, l11, fy), fz);
}

template <bool HALF>
__global__ __launch_bounds__(64)
void render_kernel(const void* __restrict__ pvv,
                   float* __restrict__ out,
                   int* __restrict__ mmi) {
    const int lane = threadIdx.x;
    const int r = blockIdx.x * 64 + lane;
    const int h = r >> 9;
    const int w = r & (PW - 1);

    const float lat = (0.5f - (float)h * (1.0f / 255.0f)) * PI_F;
    const float lon = (-0.5f - 2.0f * (float)w * (1.0f / 511.0f)) * PI_F;
    float cl, sl, clon, slon;
    __sincosf(lat, &sl, &cl);
    __sincosf(lon, &slon, &clon);
    const float sxd = cl * clon * (128.0f / NS);
    const float syd = -cl * slon * (128.0f / NS);
    const float szd = sl * (65.0f / NS);
    const float intv = 64.0f / (float)NS;

    // Ray-box clip: samples outside the padded box are exactly sigma=0,
    // and the box is convex so exit is final. Samples s=1..nrun are marched.
    const float m = 1e-3f;
    float nx = 1e9f, ny = 1e9f, nz = 1e9f;
    if (sxd >  1e-8f) nx = (256.0f - m - 127.5f) / sxd;
    if (sxd < -1e-8f) nx = (127.5f - (-1.0f + m)) / (-sxd);
    if (syd >  1e-8f) ny = (256.0f - m - 127.5f) / syd;
    if (syd < -1e-8f) ny = (127.5f - (-1.0f + m)) / (-syd);
    if (szd >  1e-8f) nz = (65.0f - m - 1.53125f) / szd;
    if (szd < -1e-8f) nz = (1.53125f - (-1.0f + m)) / (-szd);
    const float nmin = fminf(fminf(nx, ny), nz);
    int nrun = NS;
    if (nmin < (float)NS) nrun = (int)nmin;
    if (nrun < 0) nrun = 0;

    float T = 1.0f, depth = 0.0f, opac = 0.0f;

    int i = 0;
    for (; i + 8 <= nrun; i += 8) {
        float sg[8];
        const float fb = (float)i;
        #pragma unroll
        for (int j = 0; j < 8; ++j)
            sg[j] = sample_sigma<HALF>(pvv, fb + (float)(j + 1), sxd, syd, szd);
        #pragma unroll
        for (int j = 0; j < 8; ++j) {
            const float e = __expf(-sg[j] * intv);
            const float prob = fmaf(-T, e, T);           // T*(1-e)
            depth = fmaf(prob, (fb + (float)(j + 1)) * intv, depth);
            opac += prob;
            T *= e;
        }
        if (T < 1e-6f) break;
    }
    if (T >= 1e-6f) {
        for (; i < nrun; ++i) {
            const float sg = sample_sigma<HALF>(pvv, (float)(i + 1), sxd, syd, szd);
            const float e = __expf(-sg * intv);
            const float prob = fmaf(-T, e, T);
            depth = fmaf(prob, (float)(i + 1) * intv, depth);
            opac += prob;
            T *= e;
            if (T < 1e-6f) break;
        }
    }

    out[r] = depth;
    out[NRAYS + r] = opac;

    // wave min/max of depth, then one atomic per wave (depth >= 0 so
    // float bit pattern ordering == numeric ordering as ints)
    float mn = depth, mx = depth;
    #pragma unroll
    for (int off = 32; off > 0; off >>= 1) {
        mn = fminf(mn, __shfl_xor(mn, off));
        mx = fmaxf(mx, __shfl_xor(mx, off));
    }
    if (lane == 0) {
        atomicMin(mmi, __float_as_int(mn));
        atomicMax(mmi + 1, __float_as_int(mx));
    }
}

__global__ __launch_bounds__(256)
void normalize_kernel(float* __restrict__ out, const int* __restrict__ mmi) {
    const int r = blockIdx.x * 256 + threadIdx.x;
    const float mn = __int_as_float(mmi[0]);
    const float mx = __int_as_float(mmi[1]);
    out[r] = (out[r] - mn) / (mx - mn);
}

extern "C" void kernel_launch(void* const* d_in, const int* in_sizes, int n_in,
                              void* d_out, int out_size, void* d_ws, size_t ws_size,
                              hipStream_t stream) {
    const float* vox = (const float*)d_in[0];
    float* out = (float*)d_out;
    char* ws = (char*)d_ws;
    int* mmi = (int*)ws;                    // 2 ints
    void* pv = (void*)(ws + WS_VOL_OFF);

    const int pblocks = (PVOX_ELEMS + 255) / 256;
    if (ws_size >= (size_t)WS_VOL_OFF + (size_t)PVOX_ELEMS * sizeof(float)) {
        pack_kernel<false><<<pblocks, 256, 0, stream>>>(vox, pv, mmi);
        render_kernel<false><<<NB64, 64, 0, stream>>>(pv, out, mmi);
    } else {
        pack_kernel<true><<<pblocks, 256, 0, stream>>>(vox, pv, mmi);
        render_kernel<true><<<NB64, 64, 0, stream>>>(pv, out, mmi);
    }
    normalize_kernel<<<NRAYS / 256, 256, 0, stream>>>(out, mmi);
}

// Round 8
// 74.840 us; speedup vs baseline: 1.0041x; 1.0041x over previous
//
#include <hip/hip_runtime.h>
#include <hip/hip_fp16.h>
#include <math.h>

// Problem constants (match reference)
#define PH 256
#define PW 512
#define NRAYS (PH * PW)     // 131072
#define NS 300
#define NB64 (NRAYS / 64)   // 2048 one-wave blocks
#define PI_F 3.14159265358979323846f

// Padded volume: P[zp][yp][xp], zp in [0,66], yp/xp in [0,257].
// Logical (zz,y,x) = (zp-1, yp-1, xp-1); zz=0 -> ground 1000, zz in [1,64] ->
// voxel[zz-1], everything else (pads) = 0. Zero padding == reference's
// out-of-range gather = 0, so the render loop needs NO bounds logic at all.
#define XS 258
#define SS (258 * 258)          // 66564
#define ZSL 67
#define PVOX_ELEMS (ZSL * SS)   // 4,459,788
#define WS_VOL_OFF 32768

__device__ __forceinline__ float lerpf(float a, float b, float f) {
    return fmaf(f, b - a, a);
}

template <bool HALF>
__global__ __launch_bounds__(256)
void pack_kernel(const float* __restrict__ vox, void* __restrict__ pv,
                 int* __restrict__ mmi) {
    const int idx = blockIdx.x * 256 + threadIdx.x;
    if (idx == 0) {
        mmi[0] = 0x7f7fffff;   // FLT_MAX bits (min accumulator)
        mmi[1] = 0;            // 0.0f bits (max accumulator, depth >= 0)
    }
    if (idx >= PVOX_ELEMS) return;
    const int zp = idx / SS;
    const int rem = idx - zp * SS;
    const int yp = rem / XS;
    const int xp = rem - yp * XS;
    const int x = xp - 1, y = yp - 1, zz = zp - 1;
    float v = 0.0f;
    if (((unsigned)x < 256u) & ((unsigned)y < 256u)) {
        if (zz == 0) v = 1000.0f;
        else if ((unsigned)(zz - 1) < 64u) v = vox[((zz - 1) << 16) + (y << 8) + x];
    }
    if (HALF) ((__half*)pv)[idx] = __float2half_rn(v);
    else      ((float*)pv)[idx] = v;
}

template <bool HALF>
__device__ __forceinline__ float sample_sigma(const void* __restrict__ pvv,
                                              float fs, float sxd, float syd, float szd) {
    const float xf = fmaf(fs, sxd, 127.5f);
    const float yf = fmaf(fs, syd, 127.5f);
    const float zf = fmaf(fs, szd, 1.53125f);
    const float xw = floorf(xf), yw = floorf(yf), zw = floorf(zf);
    const float fx = xf - xw, fy = yf - yw, fz = zf - zw;
    const int x0 = (int)xw, y0 = (int)yw, z0 = (int)zw;
    const int off = z0 * SS + y0 * XS + x0 + (SS + XS + 1);   // +1 pad shift each axis
    float c000, c001, c010, c011, c100, c101, c110, c111;
    if (HALF) {
        const __half* p = (const __half*)pvv + off;
        c000 = __half2float(p[0]);       c001 = __half2float(p[1]);
        c010 = __half2float(p[XS]);      c011 = __half2float(p[XS + 1]);
        c100 = __half2float(p[SS]);      c101 = __half2float(p[SS + 1]);
        c110 = __half2float(p[SS + XS]); c111 = __half2float(p[SS + XS + 1]);
    } else {
        const float* p = (const float*)pvv + off;
        c000 = p[0];       c001 = p[1];
        c010 = p[XS];      c011 = p[XS + 1];
        c100 = p[SS];      c101 = p[SS + 1];
        c110 = p[SS + XS]; c111 = p[SS + XS + 1];
    }
    const float l00 = lerpf(c000, c001, fx);
    const float l01 = lerpf(c010, c011, fx);
    const float l10 = lerpf(c100, c101, fx);
    const float l11 = lerpf(c110, c111, fx);
    return lerpf(lerpf(l00, l01, fy), lerpf(l10, l11, fy), fz);
}

template <bool HALF>
__global__ __launch_bounds__(64)
void render_kernel(const void* __restrict__ pvv,
                   float* __restrict__ out,
                   int* __restrict__ mmi) {
    const int lane = threadIdx.x;
    const int r = blockIdx.x * 64 + lane;
    const int h = r >> 9;
    const int w = r & (PW - 1);

    const float lat = (0.5f - (float)h * (1.0f / 255.0f)) * PI_F;
    const float lon = (-0.5f - 2.0f * (float)w * (1.0f / 511.0f)) * PI_F;
    float cl, sl, clon, slon;
    __sincosf(lat, &sl, &cl);
    __sincosf(lon, &slon, &clon);
    const float sxd = cl * clon * (128.0f / NS);
    const float syd = -cl * slon * (128.0f / NS);
    const float szd = sl * (65.0f / NS);
    const float intv = 64.0f / (float)NS;

    // Ray-box clip: samples outside the padded box are exactly sigma=0,
    // and the box is convex so exit is final. Samples s=1..nrun are marched.
    const float m = 1e-3f;
    float nx = 1e9f, ny = 1e9f, nz = 1e9f;
    if (sxd >  1e-8f) nx = (256.0f - m - 127.5f) / sxd;
    if (sxd < -1e-8f) nx = (127.5f - (-1.0f + m)) / (-sxd);
    if (syd >  1e-8f) ny = (256.0f - m - 127.5f) / syd;
    if (syd < -1e-8f) ny = (127.5f - (-1.0f + m)) / (-syd);
    if (szd >  1e-8f) nz = (65.0f - m - 1.53125f) / szd;
    if (szd < -1e-8f) nz = (1.53125f - (-1.0f + m)) / (-szd);
    const float nmin = fminf(fminf(nx, ny), nz);
    int nrun = NS;
    if (nmin < (float)NS) nrun = (int)nmin;
    if (nrun < 0) nrun = 0;

    float T = 1.0f, depth = 0.0f, opac = 0.0f, dval = 0.0f;

    int i = 0;
    for (; i + 4 <= nrun; i += 4) {
        float sg[4];
        const float fb = (float)i;
        #pragma unroll
        for (int j = 0; j < 4; ++j)
            sg[j] = sample_sigma<HALF>(pvv, fb + (float)(j + 1), sxd, syd, szd);
        #pragma unroll
        for (int j = 0; j < 4; ++j) {
            const float e = __expf(-sg[j] * intv);
            const float prob = fmaf(-T, e, T);     // T*(1-e)
            dval += intv;
            depth = fmaf(prob, dval, depth);
            opac += prob;
            T *= e;
        }
        if (T < 1e-6f) break;
    }
    if (T >= 1e-6f) {
        for (; i < nrun; ++i) {
            const float sg = sample_sigma<HALF>(pvv, (float)(i + 1), sxd, syd, szd);
            const float e = __expf(-sg * intv);
            const float prob = fmaf(-T, e, T);
            dval += intv;
            depth = fmaf(prob, dval, depth);
            opac += prob;
            T *= e;
            if (T < 1e-6f) break;
        }
    }

    out[r] = depth;
    out[NRAYS + r] = opac;

    // wave min/max of depth, then one atomic per wave (depth >= 0 so
    // float bit pattern ordering == numeric ordering as ints)
    float mn = depth, mx = depth;
    #pragma unroll
    for (int off = 32; off > 0; off >>= 1) {
        mn = fminf(mn, __shfl_xor(mn, off));
        mx = fmaxf(mx, __shfl_xor(mx, off));
    }
    if (lane == 0) {
        atomicMin(mmi, __float_as_int(mn));
        atomicMax(mmi + 1, __float_as_int(mx));
    }
}

__global__ __launch_bounds__(256)
void normalize_kernel(float* __restrict__ out, const int* __restrict__ mmi) {
    const int r = blockIdx.x * 256 + threadIdx.x;
    const float mn = __int_as_float(mmi[0]);
    const float mx = __int_as_float(mmi[1]);
    out[r] = (out[r] - mn) / (mx - mn);
}

extern "C" void kernel_launch(void* const* d_in, const int* in_sizes, int n_in,
                              void* d_out, int out_size, void* d_ws, size_t ws_size,
                              hipStream_t stream) {
    const float* vox = (const float*)d_in[0];
    float* out = (float*)d_out;
    char* ws = (char*)d_ws;
    int* mmi = (int*)ws;                    // 2 ints
    void* pv = (void*)(ws + WS_VOL_OFF);

    const int pblocks = (PVOX_ELEMS + 255) / 256;
    if (ws_size >= (size_t)WS_VOL_OFF + (size_t)PVOX_ELEMS * sizeof(float)) {
        pack_kernel<false><<<pblocks, 256, 0, stream>>>(vox, pv, mmi);
        render_kernel<false><<<NB64, 64, 0, stream>>>(pv, out, mmi);
    } else {
        pack_kernel<true><<<pblocks, 256, 0, stream>>>(vox, pv, mmi);
        render_kernel<true><<<NB64, 64, 0, stream>>>(pv, out, mmi);
    }
    normalize_kernel<<<NRAYS / 256, 256, 0, stream>>>(out, mmi);
}

// Round 9
// 49.994 us; speedup vs baseline: 1.5032x; 1.4970x over previous
//
#include <hip/hip_runtime.h>
#include <hip/hip_fp16.h>
#include <math.h>

// Problem constants (match reference)
#define PH 256
#define PW 512
#define NRAYS (PH * PW)     // 131072
#define NS 300
#define NB64 (NRAYS / 64)   // 2048 one-wave blocks
#define PI_F 3.14159265358979323846f

// Padded volume: P[zp][yp][xp], zp in [0,66], yp/xp in [0,257].
// Logical (zz,y,x) = (zp-1, yp-1, xp-1); zz=0 -> ground 1000, zz in [1,64] ->
// voxel[zz-1], everything else (pads) = 0. Zero padding == reference's
// out-of-range gather = 0, so the render loop needs NO bounds logic at all.
#define XS 258
#define SS (258 * 258)          // 66564
#define ZSL 67
#define PVOX_ELEMS (ZSL * SS)   // 4,459,788
#define WS_VOL_OFF 32768

__device__ __forceinline__ float lerpf(float a, float b, float f) {
    return fmaf(f, b - a, a);
}

template <bool HALF>
__global__ __launch_bounds__(256)
void pack_kernel(const float* __restrict__ vox, void* __restrict__ pv) {
    const int idx = blockIdx.x * 256 + threadIdx.x;
    if (idx >= PVOX_ELEMS) return;
    const int zp = idx / SS;
    const int rem = idx - zp * SS;
    const int yp = rem / XS;
    const int xp = rem - yp * XS;
    const int x = xp - 1, y = yp - 1, zz = zp - 1;
    float v = 0.0f;
    if (((unsigned)x < 256u) & ((unsigned)y < 256u)) {
        if (zz == 0) v = 1000.0f;
        else if ((unsigned)(zz - 1) < 64u) v = vox[((zz - 1) << 16) + (y << 8) + x];
    }
    if (HALF) ((__half*)pv)[idx] = __float2half_rn(v);
    else      ((float*)pv)[idx] = v;
}

template <bool HALF>
__device__ __forceinline__ float sample_sigma(const void* __restrict__ pvv,
                                              float fs, float sxd, float syd, float szd) {
    const float xf = fmaf(fs, sxd, 127.5f);
    const float yf = fmaf(fs, syd, 127.5f);
    const float zf = fmaf(fs, szd, 1.53125f);
    const float xw = floorf(xf), yw = floorf(yf), zw = floorf(zf);
    const float fx = xf - xw, fy = yf - yw, fz = zf - zw;
    const int x0 = (int)xw, y0 = (int)yw, z0 = (int)zw;
    const int off = z0 * SS + y0 * XS + x0 + (SS + XS + 1);   // +1 pad shift each axis
    float c000, c001, c010, c011, c100, c101, c110, c111;
    if (HALF) {
        const __half* p = (const __half*)pvv + off;
        c000 = __half2float(p[0]);       c001 = __half2float(p[1]);
        c010 = __half2float(p[XS]);      c011 = __half2float(p[XS + 1]);
        c100 = __half2float(p[SS]);      c101 = __half2float(p[SS + 1]);
        c110 = __half2float(p[SS + XS]); c111 = __half2float(p[SS + XS + 1]);
    } else {
        const float* p = (const float*)pvv + off;
        c000 = p[0];       c001 = p[1];
        c010 = p[XS];      c011 = p[XS + 1];
        c100 = p[SS];      c101 = p[SS + 1];
        c110 = p[SS + XS]; c111 = p[SS + XS + 1];
    }
    const float l00 = lerpf(c000, c001, fx);
    const float l01 = lerpf(c010, c011, fx);
    const float l10 = lerpf(c100, c101, fx);
    const float l11 = lerpf(c110, c111, fx);
    return lerpf(lerpf(l00, l01, fy), lerpf(l10, l11, fy), fz);
}

template <bool HALF>
__global__ __launch_bounds__(64)
void render_kernel(const void* __restrict__ pvv,
                   float* __restrict__ out,
                   float* __restrict__ bmin, float* __restrict__ bmax) {
    const int lane = threadIdx.x;
    const int r = blockIdx.x * 64 + lane;
    const int h = r >> 9;
    const int w = r & (PW - 1);

    const float lat = (0.5f - (float)h * (1.0f / 255.0f)) * PI_F;
    const float lon = (-0.5f - 2.0f * (float)w * (1.0f / 511.0f)) * PI_F;
    float cl, sl, clon, slon;
    __sincosf(lat, &sl, &cl);
    __sincosf(lon, &slon, &clon);
    const float sxd = cl * clon * (128.0f / NS);
    const float syd = -cl * slon * (128.0f / NS);
    const float szd = sl * (65.0f / NS);
    const float intv = 64.0f / (float)NS;

    // Ray-box clip: samples with pos outside box have exactly sigma=0 (pads),
    // and the box is convex so once out, always out. Samples s=1..nrun valid.
    const float m = 1e-3f;
    float nx = 1e9f, ny = 1e9f, nz = 1e9f;
    if (sxd >  1e-8f) nx = (256.0f - m - 127.5f) / sxd;
    if (sxd < -1e-8f) nx = (127.5f - (-1.0f + m)) / (-sxd);
    if (syd >  1e-8f) ny = (256.0f - m - 127.5f) / syd;
    if (syd < -1e-8f) ny = (127.5f - (-1.0f + m)) / (-syd);
    if (szd >  1e-8f) nz = (65.0f - m - 1.53125f) / szd;
    if (szd < -1e-8f) nz = (1.53125f - (-1.0f + m)) / (-szd);
    const float nmin = fminf(fminf(nx, ny), nz);
    int nrun = NS;
    if (nmin < (float)NS) nrun = (int)nmin;
    if (nrun < 0) nrun = 0;

    float T = 1.0f, depth = 0.0f, opac = 0.0f, dval = 0.0f;

    int i = 0;
    for (; i + 4 <= nrun; i += 4) {
        float sg[4];
        const float fb = (float)i;
        #pragma unroll
        for (int j = 0; j < 4; ++j)
            sg[j] = sample_sigma<HALF>(pvv, fb + (float)(j + 1), sxd, syd, szd);
        #pragma unroll
        for (int j = 0; j < 4; ++j) {
            const float e = __expf(-sg[j] * intv);
            const float prob = fmaf(-T, e, T);     // T*(1-e)
            dval += intv;
            depth = fmaf(prob, dval, depth);
            opac += prob;
            T *= e;
        }
        if (T < 1e-6f) break;
    }
    if (T >= 1e-6f) {
        for (; i < nrun; ++i) {
            const float sg = sample_sigma<HALF>(pvv, (float)(i + 1), sxd, syd, szd);
            const float e = __expf(-sg * intv);
            const float prob = fmaf(-T, e, T);
            dval += intv;
            depth = fmaf(prob, dval, depth);
            opac += prob;
            T *= e;
            if (T < 1e-6f) break;
        }
    }

    out[r] = depth;
    out[NRAYS + r] = opac;

    // wave min/max of depth
    float mn = depth, mx = depth;
    #pragma unroll
    for (int off = 32; off > 0; off >>= 1) {
        mn = fminf(mn, __shfl_xor(mn, off));
        mx = fmaxf(mx, __shfl_xor(mx, off));
    }
    if (lane == 0) {
        bmin[blockIdx.x] = mn;
        bmax[blockIdx.x] = mx;
    }
}

__global__ __launch_bounds__(256)
void reduce_minmax_kernel(const float* __restrict__ blockMin,
                          const float* __restrict__ blockMax,
                          float* __restrict__ mm) {
    __shared__ float smn[256];
    __shared__ float smx[256];
    const int t = threadIdx.x;
    float mn = 1e30f, mx = -1e30f;
    for (int i = t; i < NB64; i += 256) {
        mn = fminf(mn, blockMin[i]);
        mx = fmaxf(mx, blockMax[i]);
    }
    smn[t] = mn;
    smx[t] = mx;
    __syncthreads();
    #pragma unroll
    for (int sft = 128; sft > 0; sft >>= 1) {
        if (t < sft) {
            smn[t] = fminf(smn[t], smn[t + sft]);
            smx[t] = fmaxf(smx[t], smx[t + sft]);
        }
        __syncthreads();
    }
    if (t == 0) {
        mm[0] = smn[0];
        mm[1] = smx[0];
    }
}

__global__ __launch_bounds__(256)
void normalize_kernel(float* __restrict__ out, const float* __restrict__ mm) {
    const int r = blockIdx.x * 256 + threadIdx.x;
    const float mn = mm[0];
    const float mx = mm[1];
    out[r] = (out[r] - mn) / (mx - mn);
}

extern "C" void kernel_launch(void* const* d_in, const int* in_sizes, int n_in,
                              void* d_out, int out_size, void* d_ws, size_t ws_size,
                              hipStream_t stream) {
    const float* vox = (const float*)d_in[0];
    float* out = (float*)d_out;
    char* ws = (char*)d_ws;
    float* bmin = (float*)ws;               // 2048 floats
    float* bmax = (float*)(ws + 8192);      // 2048 floats
    float* mm   = (float*)(ws + 16384);     // 2 floats
    void* pv = (void*)(ws + WS_VOL_OFF);

    const int pblocks = (PVOX_ELEMS + 255) / 256;
    if (ws_size >= (size_t)WS_VOL_OFF + (size_t)PVOX_ELEMS * sizeof(float)) {
        pack_kernel<false><<<pblocks, 256, 0, stream>>>(vox, pv);
        render_kernel<false><<<NB64, 64, 0, stream>>>(pv, out, bmin, bmax);
    } else {
        pack_kernel<true><<<pblocks, 256, 0, stream>>>(vox, pv);
        render_kernel<true><<<NB64, 64, 0, stream>>>(pv, out, bmin, bmax);
    }
    reduce_minmax_kernel<<<1, 256, 0, stream>>>(bmin, bmax, mm);
    normalize_kernel<<<NRAYS / 256, 256, 0, stream>>>(out, mm);
}